// Round 11
// baseline (225.063 us; speedup 1.0000x reference)
//
#include <hip/hip_runtime.h>
#include <math.h>

#define TEMP_F   0.5f
#define ALPHA_F  1.0f
#define BETA_F   5.5f
#define GAMMA_F  5.0f
#define N_IMG    400
#define D_DIM    512
#define C_CLS    1000
#define C_PAD    1024
#define M_SUP    16000

typedef __attribute__((ext_vector_type(8))) short short8;
typedef __attribute__((ext_vector_type(4))) short short4v;
typedef __attribute__((ext_vector_type(4))) float f32x4;

// ---------- helpers ----------
__device__ __forceinline__ short f2bf(float f) {
    unsigned u = __float_as_uint(f);
    unsigned r = (u + 0x7fffu + ((u >> 16) & 1u)) >> 16;
    return (short)r;
}
__device__ __forceinline__ float bf2f(short s) {
    return __uint_as_float(((unsigned)(unsigned short)s) << 16);
}
__device__ __forceinline__ unsigned encf(float f) {
    unsigned u = __float_as_uint(f);
    return (u & 0x80000000u) ? ~u : (u | 0x80000000u);
}
__device__ __forceinline__ float decf(unsigned u) {
    return (u & 0x80000000u) ? __uint_as_float(u & 0x7FFFFFFFu) : __uint_as_float(~u);
}

__device__ __forceinline__ float block_reduce_sum(float v) {
    __shared__ float red[4];
    #pragma unroll
    for (int o = 32; o > 0; o >>= 1) v += __shfl_down(v, o, 64);
    int w = threadIdx.x >> 6, l = threadIdx.x & 63;
    __syncthreads();
    if (l == 0) red[w] = v;
    __syncthreads();
    float r = red[0];
    int nw = blockDim.x >> 6;
    for (int i = 1; i < nw; ++i) r += red[i];
    return r;
}

__device__ __forceinline__ void gload_lds16(const void* g, void* l) {
    __builtin_amdgcn_global_load_lds(
        (const __attribute__((address_space(1))) unsigned int*)g,
        (__attribute__((address_space(3))) unsigned int*)l, 16, 0, 0);
}

// ---------- shared GEMM body ----------
// bf16 MFMA GEMM tile: C[i,j] = alpha * sum_k A[i,k]*B[j,k]
// 128x128 tile, BK=32, 4 waves, 3-buffer counted-vmcnt 2-barrier pipeline
// (round-7 configuration verbatim - best measured; rounds 8/9/10 proved all
// schedule micro-variants null-or-worse at this problem size).
// No vmem stores outstanding during the K-loop (round-3 lesson).
// EPILOGUE ATOMIC RULE (round-5/6, confirmed): same-address minmax funnels
// through LDS to ONE atomicMin + ONE atomicMax per block. Distinct-address
// atomics (EPI=5's per-row se[] adds, contention <=8) are fine.
// EPI: 1 = bf16 store
//      2 = kl transform: v = ent[i] - v + logf(se[j]); fp32 store + minmax
//          mm[0..1]  (se passed via 'lse' param; no-max LSE is fp32-exact
//          because train logits are in [-2.05, 2.05])
//      3 = fp32 store + minmax mm[2..3]
//      4 = fp32 store + 100*v pre-fill into out2 [I x C_CLS]
//      5 = NO store; per-row sum of exp(v) over cols < Jout, shuffle-reduced
//          across the 16 fr-lanes, atomicAdd into se[row] (passed via out2).
//          Fuses train-logit row-LSE into GEMM1: tb (32MB wr + 64MB rd) and
//          the row_lse dispatch are eliminated.
template<int EPI>
__device__ __forceinline__ void gemm_body(
    const short* __restrict__ A, const short* __restrict__ B, void* __restrict__ Cm,
    int I, int Jclamp, int Jout, int K, long lda, long ldb, long ldc, float alpha,
    const float* __restrict__ ent, const float* __restrict__ lse,
    unsigned* __restrict__ mm, float* __restrict__ out2,
    int i0, int j0, short (*As)[4096], short (*Bs)[4096])
{
    const int tid = threadIdx.x;
    const int wave = tid >> 6;
    const int lane = tid & 63;

    const int srow = wave * 16 + (lane >> 2);  // staging row within 64-row group
    const int skk  = (lane & 3) * 8;           // staging k offset (bf16 elems)

    const int wm = (wave & 1) * 64;
    const int wn = (wave >> 1) * 64;
    const int fr = lane & 15;   // fragment row/col
    const int fq = lane >> 4;   // quad

    f32x4 acc[4][4] = {};

    auto stage = [&](int buf, int k0) {
        #pragma unroll
        for (int q = 0; q < 2; ++q) {
            int gi = i0 + q * 64 + srow; if (gi > I - 1) gi = I - 1;
            gload_lds16(A + (long)gi * lda + k0 + skk, As[buf] + q * 2048 + wave * 512);
        }
        #pragma unroll
        for (int q = 0; q < 2; ++q) {
            int gj = j0 + q * 64 + srow; if (gj > Jclamp - 1) gj = Jclamp - 1;
            gload_lds16(B + (long)gj * ldb + k0 + skk, Bs[buf] + q * 2048 + wave * 512);
        }
    };

    const int nt = K >> 5;                 // 16 or 32
    stage(0, 0);
    if (nt > 1) stage(1, 32);
    if (nt > 2) stage(2, 64);              // 12 loads/wave outstanding

    for (int t = 0; t < nt; ++t) {
        const int b = t % 3;

        // wait for tile t's 4 loads (this wave); keep t+1,t+2 in flight
        if (t + 2 < nt)      asm volatile("s_waitcnt vmcnt(8)" ::: "memory");
        else if (t + 1 < nt) asm volatile("s_waitcnt vmcnt(4)" ::: "memory");
        else                 asm volatile("s_waitcnt vmcnt(0)" ::: "memory");
        __builtin_amdgcn_s_barrier();      // all waves' tile-t staging visible
        __builtin_amdgcn_sched_barrier(0);

        short8 af[4], bfr[4];
        #pragma unroll
        for (int mi = 0; mi < 4; ++mi)
            af[mi] = *(const short8*)(As[b] + (wm + mi * 16 + fr) * 32 + fq * 8);
        #pragma unroll
        for (int ni = 0; ni < 4; ++ni)
            bfr[ni] = *(const short8*)(Bs[b] + (wn + ni * 16 + fr) * 32 + fq * 8);

        asm volatile("s_waitcnt lgkmcnt(0)" ::: "memory");   // frags in regs
        __builtin_amdgcn_sched_barrier(0);
        __builtin_amdgcn_s_barrier();      // all waves done READING buf b

        if (t + 3 < nt) stage(b, (t + 3) << 5);   // restage freed buffer

        __builtin_amdgcn_s_setprio(1);
        #pragma unroll
        for (int mi = 0; mi < 4; ++mi)
            #pragma unroll
            for (int ni = 0; ni < 4; ++ni)
                acc[mi][ni] = __builtin_amdgcn_mfma_f32_16x16x32_bf16(
                    af[mi], bfr[ni], acc[mi][ni], 0, 0, 0);
        __builtin_amdgcn_s_setprio(0);
    }

    if (EPI == 5) {
        // fused row-LSE partial: rs[mi][t] = sum over my 4 cols of exp(v)
        float rs[4][4];
        #pragma unroll
        for (int mi = 0; mi < 4; ++mi)
            #pragma unroll
            for (int t = 0; t < 4; ++t) rs[mi][t] = 0.f;
        #pragma unroll
        for (int mi = 0; mi < 4; ++mi)
            #pragma unroll
            for (int ni = 0; ni < 4; ++ni) {
                int gj = j0 + wn + ni * 16 + fr;
                if (gj < Jout) {
                    #pragma unroll
                    for (int t = 0; t < 4; ++t)
                        rs[mi][t] += __expf(alpha * acc[mi][ni][t]);
                }
            }
        // reduce across the 16 fr-lanes (same fq -> same rows)
        #pragma unroll
        for (int o = 1; o <= 8; o <<= 1)
            #pragma unroll
            for (int mi = 0; mi < 4; ++mi)
                #pragma unroll
                for (int t = 0; t < 4; ++t)
                    rs[mi][t] += __shfl_xor(rs[mi][t], o, 64);
        if ((lane & 15) == 0) {
            #pragma unroll
            for (int mi = 0; mi < 4; ++mi)
                #pragma unroll
                for (int t = 0; t < 4; ++t)
                    atomicAdd(out2 + (i0 + wm + mi * 16 + fq * 4 + t), rs[mi][t]);
        }
        return;
    }

    float lmin = INFINITY, lmax = -INFINITY;

    #pragma unroll
    for (int mi = 0; mi < 4; ++mi) {
        #pragma unroll
        for (int ni = 0; ni < 4; ++ni) {
            int gj = j0 + wn + ni * 16 + fr;
            float lsev = 0.f;
            if (EPI == 2) lsev = __logf(lse[gj < Jout ? gj : (Jout - 1)]);
            #pragma unroll
            for (int t = 0; t < 4; ++t) {
                int gi = i0 + wm + mi * 16 + fq * 4 + t;
                float v = alpha * acc[mi][ni][t];
                if (EPI == 2) {
                    int gic = gi < I ? gi : (I - 1);
                    v = ent[gic] - v + lsev;
                }
                if (EPI == 2 || EPI == 3) { lmin = fminf(lmin, v); lmax = fmaxf(lmax, v); }
                if (gi < I && gj < Jout) {
                    if (EPI == 1) ((short*)Cm)[(long)gi * ldc + gj] = f2bf(v);
                    else          ((float*)Cm)[(long)gi * ldc + gj] = v;
                }
                if (EPI == 4 && gi < I && gj < C_CLS)
                    out2[(long)gi * C_CLS + gj] = 100.f * v;
            }
        }
    }

    if (EPI == 2 || EPI == 3) {
        // per-wave shuffle reduce -> LDS -> ONE atomicMin/Max per block.
        #pragma unroll
        for (int o = 32; o > 0; o >>= 1) {
            lmin = fminf(lmin, __shfl_down(lmin, o, 64));
            lmax = fmaxf(lmax, __shfl_down(lmax, o, 64));
        }
        __shared__ float rmin[4], rmax[4];
        if (lane == 0) { rmin[wave] = lmin; rmax[wave] = lmax; }
        __syncthreads();
        if (tid == 0) {
            float bmin = fminf(fminf(rmin[0], rmin[1]), fminf(rmin[2], rmin[3]));
            float bmax = fmaxf(fmaxf(rmax[0], rmax[1]), fmaxf(rmax[2], rmax[3]));
            const int base = (EPI == 2) ? 0 : 2;
            atomicMin(&mm[base + 0], encf(bmin));
            atomicMax(&mm[base + 1], encf(bmax));
        }
    }
}

// ---------- kernels ----------

// prep: init mm + normalize text rows -> Tnb AND TnT (blocks 0..999; blocks
// 0..23 also zero TnT's pad cols 1000..1023 - workspace is poisoned and
// NaN*0 = NaN in MFMA) + normalize image rows (1000..1399) + transpose S
// into Sb (1400..3399) + zero se[16000] (3400..3415).
__global__ __launch_bounds__(256) void prep_k(
    const float* __restrict__ text_embeds, const float* __restrict__ image_features,
    const float* __restrict__ S,
    short* __restrict__ Tnb, short* __restrict__ TnT, short* __restrict__ imgb,
    short* __restrict__ Sb, float* __restrict__ se, unsigned* __restrict__ mm)
{
    const int b = blockIdx.x;
    if (b == 0 && threadIdx.x < 4)
        mm[threadIdx.x] = (threadIdx.x & 1) ? encf(-INFINITY) : encf(INFINITY);

    if (b < 1000) {
        const float* s = text_embeds + (long)b * D_DIM;
        short* d = Tnb + (long)b * D_DIM;
        float ss = 0.f;
        for (int c = threadIdx.x; c < D_DIM; c += 256) { float v = s[c]; ss += v * v; }
        float tot = block_reduce_sum(ss);
        float inv = 1.0f / fmaxf(sqrtf(tot), 1e-12f);
        for (int c = threadIdx.x; c < D_DIM; c += 256) {
            short bv = f2bf(s[c] * inv);
            d[c] = bv;
            TnT[(long)c * C_PAD + b] = bv;       // transposed copy [512 x 1024]
        }
        if (b < 24)
            for (int f = threadIdx.x; f < D_DIM; f += 256)
                TnT[(long)f * C_PAD + 1000 + b] = 0;   // zero pad cols
    } else if (b < 1400) {
        const float* s = image_features + (long)(b - 1000) * D_DIM;
        short* d = imgb + (long)(b - 1000) * D_DIM;
        float ss = 0.f;
        for (int c = threadIdx.x; c < D_DIM; c += 256) { float v = s[c]; ss += v * v; }
        float tot = block_reduce_sum(ss);
        float inv = 1.0f / fmaxf(sqrtf(tot), 1e-12f);
        for (int c = threadIdx.x; c < D_DIM; c += 256) d[c] = f2bf(s[c] * inv);
    } else if (b < 3400) {
        __shared__ float tile[64][65];
        int l = b - 1400;
        int m0 = (l % 250) * 64, d0 = (l / 250) * 64;
        int ml = (threadIdx.x & 15) * 4;
        int dl = threadIdx.x >> 4;
        #pragma unroll
        for (int r = 0; r < 64; r += 16) {
            f32x4 v = *(const f32x4*)(S + (long)(d0 + dl + r) * M_SUP + m0 + ml);
            tile[dl + r][ml + 0] = v[0];
            tile[dl + r][ml + 1] = v[1];
            tile[dl + r][ml + 2] = v[2];
            tile[dl + r][ml + 3] = v[3];
        }
        __syncthreads();
        int mw = threadIdx.x >> 4;
        int dc = (threadIdx.x & 15) * 4;
        #pragma unroll
        for (int r = 0; r < 64; r += 16) {
            short4v o;
            #pragma unroll
            for (int k = 0; k < 4; ++k) o[k] = f2bf(tile[dc + k][mw + r]);
            *(short4v*)(Sb + (long)(m0 + mw + r) * D_DIM + d0 + dc) = o;
        }
    } else {
        int base = (b - 3400) * 1000;
        for (int i = threadIdx.x; i < 1000; i += 256) se[base + i] = 0.f;
    }
}

// mega GEMM: three independent GEMMs in one dispatch (grid-partition fusion).
// blocks [0,1000):    GEMM1 (EPI=5) exp-row-sums of 2*Sb.Tnb^T -> se[]
//   (125 i x 8 j, bijective XCD swizzle; NO tb store - fused LSE)
// blocks [1000,1512): GEMM3 nk = imgb.Sb^T (4 i x 128 j, XCD-grouped)
//                     + minmax mm[2..3]
// blocks [1512,1544): GEMM0 dot = imgb.Tnb^T (4 i x 8 j) + out prefill
__global__ __launch_bounds__(256) void mega_gemm_k(
    const short* __restrict__ Sb, const short* __restrict__ Tnb,
    const short* __restrict__ imgb,
    float* __restrict__ se, float* __restrict__ nk, float* __restrict__ dot,
    unsigned* __restrict__ mm, float* __restrict__ out)
{
    __shared__ short As[3][4096];
    __shared__ short Bs[3][4096];
    const int lin = blockIdx.x;

    if (lin < 1000) {
        int gt = (lin & 7) * 125 + (lin >> 3);   // bijective [0,1000)
        int i0 = (gt >> 3) * 128;                // 125 i-tiles
        int j0 = (gt & 7) * 128;                 // 8 j-tiles
        gemm_body<5>(Sb, Tnb, nullptr, M_SUP, C_CLS, C_CLS, D_DIM, D_DIM, D_DIM, 0,
                     2.0f, nullptr, nullptr, nullptr, se, i0, j0, As, Bs);
    } else if (lin < 1512) {
        int l = lin - 1000;
        int xcd = l & 7;
        int idx = l >> 3;
        int i0 = (idx & 3) * 128;
        int j0 = (xcd * 16 + (idx >> 2)) * 128;
        gemm_body<3>(imgb, Sb, nk, N_IMG, M_SUP, M_SUP, D_DIM, D_DIM, D_DIM, M_SUP,
                     1.0f, nullptr, nullptr, mm, nullptr, i0, j0, As, Bs);
    } else {
        int l = lin - 1512;                      // 32 blocks: 4 i x 8 j
        int i0 = (l >> 3) * 128;
        int j0 = (l & 7) * 128;
        gemm_body<4>(imgb, Tnb, dot, N_IMG, C_CLS, C_PAD, D_DIM, D_DIM, D_DIM, C_PAD,
                     1.0f, nullptr, nullptr, nullptr, out, i0, j0, As, Bs);
    }
}

// test softmax: logits = 2*dot; one wave per row; writes p bf16 (pad zeros)
// and entropy. 100 blocks x 4 waves.
__global__ void softmax_k(const float* __restrict__ dot, short* __restrict__ pb,
                          float* __restrict__ ent)
{
    const int lane = threadIdx.x & 63;
    int n = blockIdx.x * 4 + (threadIdx.x >> 6);
    const float* dr = dot + (long)n * C_PAD;
    short* pr = pb + (long)n * C_PAD;
    f32x4 v[4];
    #pragma unroll
    for (int pp = 0; pp < 4; ++pp)
        v[pp] = *(const f32x4*)(dr + pp * 256 + lane * 4);
    float mx = -INFINITY;
    #pragma unroll
    for (int pp = 0; pp < 4; ++pp) {
        bool valid = (pp < 3) || (lane < 58);   // col 768+lane*4 < 1000
        if (valid)
            #pragma unroll
            for (int j = 0; j < 4; ++j) mx = fmaxf(mx, 2.f * v[pp][j]);
    }
    #pragma unroll
    for (int o = 32; o > 0; o >>= 1) mx = fmaxf(mx, __shfl_xor(mx, o, 64));
    float se = 0.f;
    #pragma unroll
    for (int pp = 0; pp < 4; ++pp) {
        bool valid = (pp < 3) || (lane < 58);
        if (valid)
            #pragma unroll
            for (int j = 0; j < 4; ++j) se += __expf(2.f * v[pp][j] - mx);
    }
    #pragma unroll
    for (int o = 32; o > 0; o >>= 1) se += __shfl_xor(se, o, 64);
    float logsum = mx + __logf(se);
    float e = 0.f;
    #pragma unroll
    for (int pp = 0; pp < 4; ++pp) {
        bool valid = (pp < 3) || (lane < 58);
        short4v o4;
        #pragma unroll
        for (int j = 0; j < 4; ++j) {
            if (valid) {
                float lp = 2.f * v[pp][j] - logsum;
                float pv = __expf(lp);
                o4[j] = f2bf(pv);
                e += pv * lp;
            } else {
                o4[j] = 0;
            }
        }
        *(short4v*)(pr + pp * 256 + lane * 4) = o4;
    }
    #pragma unroll
    for (int o = 32; o > 0; o >>= 1) e += __shfl_xor(e, o, 64);
    if (lane == 0) ent[n] = e;
}

// W GEMM: Wb[n,d] = 2 * sum_c pb[n,c] * TnT[d,c]   (= 2*pb.Tnb, bf16 store)
// 16 blocks (4 i x 4 j), K=1024. pb pad cols are exact zeros; TnT pad cols
// zeroed in prep -> K-pad contributes 0.
__global__ __launch_bounds__(256) void wgemm_k(
    const short* __restrict__ pb, const short* __restrict__ TnT,
    short* __restrict__ Wb)
{
    __shared__ short As[3][4096];
    __shared__ short Bs[3][4096];
    int i0 = (blockIdx.x >> 2) * 128;
    int j0 = (blockIdx.x & 3) * 128;
    gemm_body<1>(pb, TnT, Wb, N_IMG, D_DIM, D_DIM, C_PAD, C_PAD, C_PAD, D_DIM,
                 2.0f, nullptr, nullptr, nullptr, nullptr, i0, j0, As, Bs);
}

// qGEMM (replaces GEMM2 via W-factorization, K halved 1024->512):
// kl[n,m] = ent[n] - Wb[n,:].Sb[m,:] + logf(se[m])  + minmax mm[0..1].
// 512 blocks: 4 i x 128 j, XCD-grouped.
__global__ __launch_bounds__(256) void qgemm_k(
    const short* __restrict__ Wb, const short* __restrict__ Sb, float* __restrict__ kl,
    const float* __restrict__ ent, const float* __restrict__ se,
    unsigned* __restrict__ mm)
{
    __shared__ short As[3][4096];
    __shared__ short Bs[3][4096];
    int lin = blockIdx.x;
    int xcd = lin & 7;
    int idx = lin >> 3;
    int i0 = (idx & 3) * 128;
    int j0 = (xcd * 16 + (idx >> 2)) * 128;
    gemm_body<2>(Wb, Sb, kl, N_IMG, M_SUP, M_SUP, D_DIM, D_DIM, D_DIM, M_SUP,
                 1.0f, ent, se, mm, nullptr, i0, j0, As, Bs);
}

// M split 4 ways (1600 blocks). float4/int4 loads. out was pre-filled with
// 100*dot by mega's GEMM0 branch; partial class bins merged with one
// coalesced global atomicAdd per class (distinct addresses, contention 4).
__global__ __launch_bounds__(256) void final_partial_k(
    const float* __restrict__ kl, const float* __restrict__ nk,
    const int* __restrict__ labels, const unsigned* __restrict__ mm,
    float* __restrict__ out)
{
    int n = blockIdx.x;
    int q = blockIdx.y;                       // 0..3, quarter of M
    __shared__ float bins[C_CLS];
    for (int c = threadIdx.x; c < C_CLS; c += 256) bins[c] = 0.f;
    __syncthreads();
    float klmin = decf(mm[0]), klmax = decf(mm[1]);
    float nkmin = decf(mm[2]), nkmax = decf(mm[3]);
    float ratio = (nkmax - nkmin) / (klmax - klmin);
    const int m0 = q * (M_SUP / 4);
    const float4* kl4 = (const float4*)(kl + (long)n * M_SUP + m0);
    const float4* nk4 = (const float4*)(nk + (long)n * M_SUP + m0);
    const int4*  lb4 = (const int4*)(labels + m0);
    const int nv = M_SUP / 4 / 4;             // 1000 float4s per quarter
    for (int v = threadIdx.x; v < nv; v += 256) {
        float4 kv = kl4[v];
        float4 vv = nk4[v];
        int4   lv = lb4[v];
        float y, contrib;
        y = (kv.x - klmin) * ratio + nkmin;
        contrib = -GAMMA_F * y + ALPHA_F * __expf(BETA_F * (vv.x - 1.0f));
        atomicAdd(&bins[lv.x], contrib);
        y = (kv.y - klmin) * ratio + nkmin;
        contrib = -GAMMA_F * y + ALPHA_F * __expf(BETA_F * (vv.y - 1.0f));
        atomicAdd(&bins[lv.y], contrib);
        y = (kv.z - klmin) * ratio + nkmin;
        contrib = -GAMMA_F * y + ALPHA_F * __expf(BETA_F * (vv.z - 1.0f));
        atomicAdd(&bins[lv.z], contrib);
        y = (kv.w - klmin) * ratio + nkmin;
        contrib = -GAMMA_F * y + ALPHA_F * __expf(BETA_F * (vv.w - 1.0f));
        atomicAdd(&bins[lv.w], contrib);
    }
    __syncthreads();
    for (int c = threadIdx.x; c < C_CLS; c += 256)
        atomicAdd(&out[(long)n * C_CLS + c], bins[c]);
}

// ---------- launch ----------
extern "C" void kernel_launch(void* const* d_in, const int* in_sizes, int n_in,
                              void* d_out, int out_size, void* d_ws, size_t ws_size,
                              hipStream_t stream) {
    const float* image_features = (const float*)d_in[0];   // [N, D]
    const float* text_embeds    = (const float*)d_in[1];   // [C, D]
    const float* support_feats  = (const float*)d_in[2];   // [D, M]
    const int*   support_labels = (const int*)d_in[3];     // [M]
    float* out = (float*)d_out;

    char* base = (char*)d_ws;
    size_t off = 0;
    auto alloc = [&](size_t bytes) {
        void* p = base + off;
        off = (off + bytes + 255) & ~(size_t)255;
        return p;
    };
    short* Tnb  = (short*)alloc(sizeof(short) * C_CLS * D_DIM);   // normalized text bf16 [C, D]
    short* TnT  = (short*)alloc(sizeof(short) * D_DIM * C_PAD);   // transposed text bf16 [D, 1024]
    short* imgb = (short*)alloc(sizeof(short) * N_IMG * D_DIM);   // normalized image bf16 [N, D]
    short* Sb   = (short*)alloc(sizeof(short) * M_SUP * D_DIM);   // support^T bf16 [M, D]
    short* pb   = (short*)alloc(sizeof(short) * N_IMG * C_PAD);   // test probs bf16 [N, 1024]
    short* Wb   = (short*)alloc(sizeof(short) * N_IMG * D_DIM);   // 2*pb.Tnb bf16 [N, D]
    float* dot  = (float*)alloc(sizeof(float) * N_IMG * C_PAD);   // img @ Tn^T fp32 [N, 1024]
    float* se   = (float*)alloc(sizeof(float) * M_SUP);           // sum_c exp(train logits)
    float* ent  = (float*)alloc(sizeof(float) * N_IMG);
    float* kl   = (float*)alloc(sizeof(float) * N_IMG * M_SUP);   // KL divergences
    float* nk   = (float*)alloc(sizeof(float) * N_IMG * M_SUP);   // img @ S
    unsigned* mm = (unsigned*)alloc(256);

    // 1. prep: init + normalize x2 (+TnT) + transpose + se zero
    prep_k<<<3416, 256, 0, stream>>>(
        text_embeds, image_features, support_feats, Tnb, TnT, imgb, Sb, se, mm);

    // 2. mega GEMM: GEMM1-fused-LSE + GEMM3 + GEMM0 (mutually independent)
    mega_gemm_k<<<1544, 256, 0, stream>>>(Sb, Tnb, imgb, se, nk, dot, mm, out);

    // 3. test softmax (needs dot)
    softmax_k<<<N_IMG / 4, 256, 0, stream>>>(dot, pb, ent);

    // 4. W GEMM (needs pb, TnT)
    wgemm_k<<<16, 256, 0, stream>>>(pb, TnT, Wb);

    // 5. qGEMM: kl + minmax (needs Wb, Sb, ent, se)
    qgemm_k<<<512, 256, 0, stream>>>(Wb, Sb, kl, ent, se, mm);

    // 6. final
    final_partial_k<<<dim3(N_IMG, 4), 256, 0, stream>>>(kl, nk, support_labels, mm, out);
}

// Round 12
// 220.007 us; speedup vs baseline: 1.0230x; 1.0230x over previous
//
#include <hip/hip_runtime.h>
#include <math.h>

#define TEMP_F   0.5f
#define ALPHA_F  1.0f
#define BETA_F   5.5f
#define GAMMA_F  5.0f
#define N_IMG    400
#define D_DIM    512
#define C_CLS    1000
#define C_PAD    1024
#define M_SUP    16000

typedef __attribute__((ext_vector_type(8))) short short8;
typedef __attribute__((ext_vector_type(4))) short short4v;
typedef __attribute__((ext_vector_type(4))) float f32x4;

// ---------- helpers ----------
__device__ __forceinline__ short f2bf(float f) {
    unsigned u = __float_as_uint(f);
    unsigned r = (u + 0x7fffu + ((u >> 16) & 1u)) >> 16;
    return (short)r;
}
__device__ __forceinline__ float bf2f(short s) {
    return __uint_as_float(((unsigned)(unsigned short)s) << 16);
}
__device__ __forceinline__ unsigned encf(float f) {
    unsigned u = __float_as_uint(f);
    return (u & 0x80000000u) ? ~u : (u | 0x80000000u);
}
__device__ __forceinline__ float decf(unsigned u) {
    return (u & 0x80000000u) ? __uint_as_float(u & 0x7FFFFFFFu) : __uint_as_float(~u);
}

__device__ __forceinline__ float block_reduce_sum(float v) {
    __shared__ float red[4];
    #pragma unroll
    for (int o = 32; o > 0; o >>= 1) v += __shfl_down(v, o, 64);
    int w = threadIdx.x >> 6, l = threadIdx.x & 63;
    __syncthreads();
    if (l == 0) red[w] = v;
    __syncthreads();
    float r = red[0];
    int nw = blockDim.x >> 6;
    for (int i = 1; i < nw; ++i) r += red[i];
    return r;
}

__device__ __forceinline__ void gload_lds16(const void* g, void* l) {
    __builtin_amdgcn_global_load_lds(
        (const __attribute__((address_space(1))) unsigned int*)g,
        (__attribute__((address_space(3))) unsigned int*)l, 16, 0, 0);
}

// ---------- shared GEMM body ----------
// bf16 MFMA GEMM tile: C[i,j] = alpha * sum_k A[i,k]*B[j,k]
// 128x128 tile, BK=32, 4 waves, 3-buffer counted-vmcnt 2-barrier pipeline
// (round-7 configuration verbatim - best measured; rounds 8/9/10 proved all
// schedule micro-variants null-or-worse at this problem size).
// No vmem stores outstanding during the K-loop (round-3 lesson).
// EPILOGUE ATOMIC RULE (round-5/6, confirmed): same-address minmax funnels
// through LDS to ONE atomicMin + ONE atomicMax per block. Distinct-address
// atomics (EPI=5's per-row se[] adds, contention 8) are fine.
// COALESCING RULE (round-11 lesson): never scatter-store (2B @ stride 2KB
// cost ~+18 us in prep); transpose via LDS tiles only.
// EPI: 1 = bf16 store
//      2 = kl transform: v = ent[i] - v + logf(se[j]); fp32 store + minmax
//          mm[0..1]  (no-max LSE is fp32-exact: train logits in [-2.05,2.05])
//      3 = fp32 store + minmax mm[2..3]
//      4 = fp32 store + 100*v pre-fill into out2 [I x C_CLS]
//      5 = NO store; per-row sum of exp(v) over cols < Jout, shuffle-reduced
//          across the 16 fr-lanes, atomicAdd into se[row] (passed via out2).
//          Fuses train-logit row-LSE into GEMM1: tb (32MB wr + 64MB rd) and
//          the row_lse dispatch are eliminated.
template<int EPI>
__device__ __forceinline__ void gemm_body(
    const short* __restrict__ A, const short* __restrict__ B, void* __restrict__ Cm,
    int I, int Jclamp, int Jout, int K, long lda, long ldb, long ldc, float alpha,
    const float* __restrict__ ent, const float* __restrict__ lse,
    unsigned* __restrict__ mm, float* __restrict__ out2,
    int i0, int j0, short (*As)[4096], short (*Bs)[4096])
{
    const int tid = threadIdx.x;
    const int wave = tid >> 6;
    const int lane = tid & 63;

    const int srow = wave * 16 + (lane >> 2);  // staging row within 64-row group
    const int skk  = (lane & 3) * 8;           // staging k offset (bf16 elems)

    const int wm = (wave & 1) * 64;
    const int wn = (wave >> 1) * 64;
    const int fr = lane & 15;   // fragment row/col
    const int fq = lane >> 4;   // quad

    f32x4 acc[4][4] = {};

    auto stage = [&](int buf, int k0) {
        #pragma unroll
        for (int q = 0; q < 2; ++q) {
            int gi = i0 + q * 64 + srow; if (gi > I - 1) gi = I - 1;
            gload_lds16(A + (long)gi * lda + k0 + skk, As[buf] + q * 2048 + wave * 512);
        }
        #pragma unroll
        for (int q = 0; q < 2; ++q) {
            int gj = j0 + q * 64 + srow; if (gj > Jclamp - 1) gj = Jclamp - 1;
            gload_lds16(B + (long)gj * ldb + k0 + skk, Bs[buf] + q * 2048 + wave * 512);
        }
    };

    const int nt = K >> 5;                 // 16 or 32
    stage(0, 0);
    if (nt > 1) stage(1, 32);
    if (nt > 2) stage(2, 64);              // 12 loads/wave outstanding

    for (int t = 0; t < nt; ++t) {
        const int b = t % 3;

        // wait for tile t's 4 loads (this wave); keep t+1,t+2 in flight
        if (t + 2 < nt)      asm volatile("s_waitcnt vmcnt(8)" ::: "memory");
        else if (t + 1 < nt) asm volatile("s_waitcnt vmcnt(4)" ::: "memory");
        else                 asm volatile("s_waitcnt vmcnt(0)" ::: "memory");
        __builtin_amdgcn_s_barrier();      // all waves' tile-t staging visible
        __builtin_amdgcn_sched_barrier(0);

        short8 af[4], bfr[4];
        #pragma unroll
        for (int mi = 0; mi < 4; ++mi)
            af[mi] = *(const short8*)(As[b] + (wm + mi * 16 + fr) * 32 + fq * 8);
        #pragma unroll
        for (int ni = 0; ni < 4; ++ni)
            bfr[ni] = *(const short8*)(Bs[b] + (wn + ni * 16 + fr) * 32 + fq * 8);

        asm volatile("s_waitcnt lgkmcnt(0)" ::: "memory");   // frags in regs
        __builtin_amdgcn_sched_barrier(0);
        __builtin_amdgcn_s_barrier();      // all waves done READING buf b

        if (t + 3 < nt) stage(b, (t + 3) << 5);   // restage freed buffer

        __builtin_amdgcn_s_setprio(1);
        #pragma unroll
        for (int mi = 0; mi < 4; ++mi)
            #pragma unroll
            for (int ni = 0; ni < 4; ++ni)
                acc[mi][ni] = __builtin_amdgcn_mfma_f32_16x16x32_bf16(
                    af[mi], bfr[ni], acc[mi][ni], 0, 0, 0);
        __builtin_amdgcn_s_setprio(0);
    }

    if (EPI == 5) {
        // fused row-LSE partial: rs[mi][t] = sum over my 4 cols of exp(v)
        float rs[4][4];
        #pragma unroll
        for (int mi = 0; mi < 4; ++mi)
            #pragma unroll
            for (int t = 0; t < 4; ++t) rs[mi][t] = 0.f;
        #pragma unroll
        for (int mi = 0; mi < 4; ++mi)
            #pragma unroll
            for (int ni = 0; ni < 4; ++ni) {
                int gj = j0 + wn + ni * 16 + fr;
                if (gj < Jout) {
                    #pragma unroll
                    for (int t = 0; t < 4; ++t)
                        rs[mi][t] += __expf(alpha * acc[mi][ni][t]);
                }
            }
        // reduce across the 16 fr-lanes (same fq -> same rows)
        #pragma unroll
        for (int o = 1; o <= 8; o <<= 1)
            #pragma unroll
            for (int mi = 0; mi < 4; ++mi)
                #pragma unroll
                for (int t = 0; t < 4; ++t)
                    rs[mi][t] += __shfl_xor(rs[mi][t], o, 64);
        if ((lane & 15) == 0) {
            #pragma unroll
            for (int mi = 0; mi < 4; ++mi)
                #pragma unroll
                for (int t = 0; t < 4; ++t)
                    atomicAdd(out2 + (i0 + wm + mi * 16 + fq * 4 + t), rs[mi][t]);
        }
        return;
    }

    float lmin = INFINITY, lmax = -INFINITY;

    #pragma unroll
    for (int mi = 0; mi < 4; ++mi) {
        #pragma unroll
        for (int ni = 0; ni < 4; ++ni) {
            int gj = j0 + wn + ni * 16 + fr;
            float lsev = 0.f;
            if (EPI == 2) lsev = __logf(lse[gj < Jout ? gj : (Jout - 1)]);
            #pragma unroll
            for (int t = 0; t < 4; ++t) {
                int gi = i0 + wm + mi * 16 + fq * 4 + t;
                float v = alpha * acc[mi][ni][t];
                if (EPI == 2) {
                    int gic = gi < I ? gi : (I - 1);
                    v = ent[gic] - v + lsev;
                }
                if (EPI == 2 || EPI == 3) { lmin = fminf(lmin, v); lmax = fmaxf(lmax, v); }
                if (gi < I && gj < Jout) {
                    if (EPI == 1) ((short*)Cm)[(long)gi * ldc + gj] = f2bf(v);
                    else          ((float*)Cm)[(long)gi * ldc + gj] = v;
                }
                if (EPI == 4 && gi < I && gj < C_CLS)
                    out2[(long)gi * C_CLS + gj] = 100.f * v;
            }
        }
    }

    if (EPI == 2 || EPI == 3) {
        // per-wave shuffle reduce -> LDS -> ONE atomicMin/Max per block.
        #pragma unroll
        for (int o = 32; o > 0; o >>= 1) {
            lmin = fminf(lmin, __shfl_down(lmin, o, 64));
            lmax = fmaxf(lmax, __shfl_down(lmax, o, 64));
        }
        __shared__ float rmin[4], rmax[4];
        if (lane == 0) { rmin[wave] = lmin; rmax[wave] = lmax; }
        __syncthreads();
        if (tid == 0) {
            float bmin = fminf(fminf(rmin[0], rmin[1]), fminf(rmin[2], rmin[3]));
            float bmax = fmaxf(fmaxf(rmax[0], rmax[1]), fmaxf(rmax[2], rmax[3]));
            const int base = (EPI == 2) ? 0 : 2;
            atomicMin(&mm[base + 0], encf(bmin));
            atomicMax(&mm[base + 1], encf(bmax));
        }
    }
}

// ---------- kernels ----------

// prep: init mm + normalize text rows -> Tnb (blocks 0..999, coalesced only;
// TnT is built later by an LDS tile-transpose - round-11's strided scatter
// here cost ~+18 us) + normalize image rows (1000..1399) + transpose S into
// Sb (1400..3399) + zero se[16000] (3400..3415).
__global__ __launch_bounds__(256) void prep_k(
    const float* __restrict__ text_embeds, const float* __restrict__ image_features,
    const float* __restrict__ S,
    short* __restrict__ Tnb, short* __restrict__ imgb,
    short* __restrict__ Sb, float* __restrict__ se, unsigned* __restrict__ mm)
{
    const int b = blockIdx.x;
    if (b == 0 && threadIdx.x < 4)
        mm[threadIdx.x] = (threadIdx.x & 1) ? encf(-INFINITY) : encf(INFINITY);

    if (b < 1400) {
        const float* s;
        short* d;
        if (b < 1000) { s = text_embeds + (long)b * D_DIM;             d = Tnb  + (long)b * D_DIM; }
        else          { s = image_features + (long)(b - 1000) * D_DIM; d = imgb + (long)(b - 1000) * D_DIM; }
        float ss = 0.f;
        for (int c = threadIdx.x; c < D_DIM; c += 256) { float v = s[c]; ss += v * v; }
        float tot = block_reduce_sum(ss);
        float inv = 1.0f / fmaxf(sqrtf(tot), 1e-12f);
        for (int c = threadIdx.x; c < D_DIM; c += 256) d[c] = f2bf(s[c] * inv);
    } else if (b < 3400) {
        __shared__ float tile[64][65];
        int l = b - 1400;
        int m0 = (l % 250) * 64, d0 = (l / 250) * 64;
        int ml = (threadIdx.x & 15) * 4;
        int dl = threadIdx.x >> 4;
        #pragma unroll
        for (int r = 0; r < 64; r += 16) {
            f32x4 v = *(const f32x4*)(S + (long)(d0 + dl + r) * M_SUP + m0 + ml);
            tile[dl + r][ml + 0] = v[0];
            tile[dl + r][ml + 1] = v[1];
            tile[dl + r][ml + 2] = v[2];
            tile[dl + r][ml + 3] = v[3];
        }
        __syncthreads();
        int mw = threadIdx.x >> 4;
        int dc = (threadIdx.x & 15) * 4;
        #pragma unroll
        for (int r = 0; r < 64; r += 16) {
            short4v o;
            #pragma unroll
            for (int k = 0; k < 4; ++k) o[k] = f2bf(tile[dc + k][mw + r]);
            *(short4v*)(Sb + (long)(m0 + mw + r) * D_DIM + d0 + dc) = o;
        }
    } else {
        int base = (b - 3400) * 1000;
        for (int i = threadIdx.x; i < 1000; i += 256) se[base + i] = 0.f;
    }
}

// mega GEMM: three independent GEMMs in one dispatch (grid-partition fusion).
// blocks [0,1000):    GEMM1 (EPI=5) exp-row-sums of 2*Sb.Tnb^T -> se[]
//   (125 i x 8 j, bijective XCD swizzle; NO tb store - fused LSE)
// blocks [1000,1512): GEMM3 nk = imgb.Sb^T (4 i x 128 j, XCD-grouped)
//                     + minmax mm[2..3]
// blocks [1512,1544): GEMM0 dot = imgb.Tnb^T (4 i x 8 j) + out prefill
__global__ __launch_bounds__(256) void mega_gemm_k(
    const short* __restrict__ Sb, const short* __restrict__ Tnb,
    const short* __restrict__ imgb,
    float* __restrict__ se, float* __restrict__ nk, float* __restrict__ dot,
    unsigned* __restrict__ mm, float* __restrict__ out)
{
    __shared__ short As[3][4096];
    __shared__ short Bs[3][4096];
    const int lin = blockIdx.x;

    if (lin < 1000) {
        int gt = (lin & 7) * 125 + (lin >> 3);   // bijective [0,1000)
        int i0 = (gt >> 3) * 128;                // 125 i-tiles
        int j0 = (gt & 7) * 128;                 // 8 j-tiles
        gemm_body<5>(Sb, Tnb, nullptr, M_SUP, C_CLS, C_CLS, D_DIM, D_DIM, D_DIM, 0,
                     2.0f, nullptr, nullptr, nullptr, se, i0, j0, As, Bs);
    } else if (lin < 1512) {
        int l = lin - 1000;
        int xcd = l & 7;
        int idx = l >> 3;
        int i0 = (idx & 3) * 128;
        int j0 = (xcd * 16 + (idx >> 2)) * 128;
        gemm_body<3>(imgb, Sb, nk, N_IMG, M_SUP, M_SUP, D_DIM, D_DIM, D_DIM, M_SUP,
                     1.0f, nullptr, nullptr, mm, nullptr, i0, j0, As, Bs);
    } else {
        int l = lin - 1512;                      // 32 blocks: 4 i x 8 j
        int i0 = (l >> 3) * 128;
        int j0 = (l & 7) * 128;
        gemm_body<4>(imgb, Tnb, dot, N_IMG, C_CLS, C_PAD, D_DIM, D_DIM, D_DIM, C_PAD,
                     1.0f, nullptr, nullptr, nullptr, out, i0, j0, As, Bs);
    }
}

// blocks [0,100): test softmax (logits = 2*dot; one wave/row; pb bf16 + ent)
// blocks [100,228): LDS tile-transpose Tnb [1000x512] -> TnT [512x1024]
//   (64x64 tiles: 16 c-tiles x 8 d-tiles; pad rows c>=1000 -> zeros;
//   coalesced short4 reads AND writes - replaces round-11's prep scatter)
__global__ __launch_bounds__(256) void sm_tr_k(
    const float* __restrict__ dot, short* __restrict__ pb, float* __restrict__ ent,
    const short* __restrict__ Tnb, short* __restrict__ TnT)
{
    const int b = blockIdx.x;
    if (b < 100) {
        const int lane = threadIdx.x & 63;
        int n = b * 4 + (threadIdx.x >> 6);
        const float* dr = dot + (long)n * C_PAD;
        short* pr = pb + (long)n * C_PAD;
        f32x4 v[4];
        #pragma unroll
        for (int pp = 0; pp < 4; ++pp)
            v[pp] = *(const f32x4*)(dr + pp * 256 + lane * 4);
        float mx = -INFINITY;
        #pragma unroll
        for (int pp = 0; pp < 4; ++pp) {
            bool valid = (pp < 3) || (lane < 58);   // col 768+lane*4 < 1000
            if (valid)
                #pragma unroll
                for (int j = 0; j < 4; ++j) mx = fmaxf(mx, 2.f * v[pp][j]);
        }
        #pragma unroll
        for (int o = 32; o > 0; o >>= 1) mx = fmaxf(mx, __shfl_xor(mx, o, 64));
        float se = 0.f;
        #pragma unroll
        for (int pp = 0; pp < 4; ++pp) {
            bool valid = (pp < 3) || (lane < 58);
            if (valid)
                #pragma unroll
                for (int j = 0; j < 4; ++j) se += __expf(2.f * v[pp][j] - mx);
        }
        #pragma unroll
        for (int o = 32; o > 0; o >>= 1) se += __shfl_xor(se, o, 64);
        float logsum = mx + __logf(se);
        float e = 0.f;
        #pragma unroll
        for (int pp = 0; pp < 4; ++pp) {
            bool valid = (pp < 3) || (lane < 58);
            short4v o4;
            #pragma unroll
            for (int j = 0; j < 4; ++j) {
                if (valid) {
                    float lp = 2.f * v[pp][j] - logsum;
                    float pv = __expf(lp);
                    o4[j] = f2bf(pv);
                    e += pv * lp;
                } else {
                    o4[j] = 0;
                }
            }
            *(short4v*)(pr + pp * 256 + lane * 4) = o4;
        }
        #pragma unroll
        for (int o = 32; o > 0; o >>= 1) e += __shfl_xor(e, o, 64);
        if (lane == 0) ent[n] = e;
    } else {
        __shared__ short tile[64][72];            // [c-in-tile][d-in-tile], +8 pad
        int b2 = b - 100;
        int c0 = (b2 & 15) * 64;                  // 16 tiles over 1024 c-cols
        int d0 = (b2 >> 4) * 64;                  // 8 tiles over 512 d-rows
        int tx = threadIdx.x & 15, ty = threadIdx.x >> 4;   // 16 x 16
        #pragma unroll
        for (int r = 0; r < 64; r += 16) {
            int c = c0 + ty + r;
            short4v v;
            if (c < C_CLS) v = *(const short4v*)(Tnb + (long)c * D_DIM + d0 + tx * 4);
            else { v[0] = 0; v[1] = 0; v[2] = 0; v[3] = 0; }
            tile[ty + r][tx * 4 + 0] = v[0];
            tile[ty + r][tx * 4 + 1] = v[1];
            tile[ty + r][tx * 4 + 2] = v[2];
            tile[ty + r][tx * 4 + 3] = v[3];
        }
        __syncthreads();
        #pragma unroll
        for (int r = 0; r < 64; r += 16) {
            int d = d0 + ty + r;
            short4v o;
            #pragma unroll
            for (int k = 0; k < 4; ++k) o[k] = tile[tx * 4 + k][ty + r];
            *(short4v*)(TnT + (long)d * C_PAD + c0 + tx * 4) = o;
        }
    }
}

// W GEMM: Wb[n,d] = 2 * sum_c pb[n,c] * TnT[d,c]   (= 2*pb.Tnb, bf16 store)
// 16 blocks (4 i x 4 j), K=1024. pb pad cols are exact zeros; TnT pad cols
// zeroed in transpose -> K-pad contributes 0.
__global__ __launch_bounds__(256) void wgemm_k(
    const short* __restrict__ pb, const short* __restrict__ TnT,
    short* __restrict__ Wb)
{
    __shared__ short As[3][4096];
    __shared__ short Bs[3][4096];
    int i0 = (blockIdx.x >> 2) * 128;
    int j0 = (blockIdx.x & 3) * 128;
    gemm_body<1>(pb, TnT, Wb, N_IMG, D_DIM, D_DIM, C_PAD, C_PAD, C_PAD, D_DIM,
                 2.0f, nullptr, nullptr, nullptr, nullptr, i0, j0, As, Bs);
}

// qGEMM (replaces GEMM2 via W-factorization, K halved 1024->512):
// kl[n,m] = ent[n] - Wb[n,:].Sb[m,:] + logf(se[m])  + minmax mm[0..1].
// 512 blocks: 4 i x 128 j, XCD-grouped.
__global__ __launch_bounds__(256) void qgemm_k(
    const short* __restrict__ Wb, const short* __restrict__ Sb, float* __restrict__ kl,
    const float* __restrict__ ent, const float* __restrict__ se,
    unsigned* __restrict__ mm)
{
    __shared__ short As[3][4096];
    __shared__ short Bs[3][4096];
    int lin = blockIdx.x;
    int xcd = lin & 7;
    int idx = lin >> 3;
    int i0 = (idx & 3) * 128;
    int j0 = (xcd * 16 + (idx >> 2)) * 128;
    gemm_body<2>(Wb, Sb, kl, N_IMG, M_SUP, M_SUP, D_DIM, D_DIM, D_DIM, M_SUP,
                 1.0f, ent, se, mm, nullptr, i0, j0, As, Bs);
}

// M split 4 ways (1600 blocks). float4/int4 loads. out was pre-filled with
// 100*dot by mega's GEMM0 branch; partial class bins merged with one
// coalesced global atomicAdd per class (distinct addresses, contention 4).
__global__ __launch_bounds__(256) void final_partial_k(
    const float* __restrict__ kl, const float* __restrict__ nk,
    const int* __restrict__ labels, const unsigned* __restrict__ mm,
    float* __restrict__ out)
{
    int n = blockIdx.x;
    int q = blockIdx.y;                       // 0..3, quarter of M
    __shared__ float bins[C_CLS];
    for (int c = threadIdx.x; c < C_CLS; c += 256) bins[c] = 0.f;
    __syncthreads();
    float klmin = decf(mm[0]), klmax = decf(mm[1]);
    float nkmin = decf(mm[2]), nkmax = decf(mm[3]);
    float ratio = (nkmax - nkmin) / (klmax - klmin);
    const int m0 = q * (M_SUP / 4);
    const float4* kl4 = (const float4*)(kl + (long)n * M_SUP + m0);
    const float4* nk4 = (const float4*)(nk + (long)n * M_SUP + m0);
    const int4*  lb4 = (const int4*)(labels + m0);
    const int nv = M_SUP / 4 / 4;             // 1000 float4s per quarter
    for (int v = threadIdx.x; v < nv; v += 256) {
        float4 kv = kl4[v];
        float4 vv = nk4[v];
        int4   lv = lb4[v];
        float y, contrib;
        y = (kv.x - klmin) * ratio + nkmin;
        contrib = -GAMMA_F * y + ALPHA_F * __expf(BETA_F * (vv.x - 1.0f));
        atomicAdd(&bins[lv.x], contrib);
        y = (kv.y - klmin) * ratio + nkmin;
        contrib = -GAMMA_F * y + ALPHA_F * __expf(BETA_F * (vv.y - 1.0f));
        atomicAdd(&bins[lv.y], contrib);
        y = (kv.z - klmin) * ratio + nkmin;
        contrib = -GAMMA_F * y + ALPHA_F * __expf(BETA_F * (vv.z - 1.0f));
        atomicAdd(&bins[lv.z], contrib);
        y = (kv.w - klmin) * ratio + nkmin;
        contrib = -GAMMA_F * y + ALPHA_F * __expf(BETA_F * (vv.w - 1.0f));
        atomicAdd(&bins[lv.w], contrib);
    }
    __syncthreads();
    for (int c = threadIdx.x; c < C_CLS; c += 256)
        atomicAdd(&out[(long)n * C_CLS + c], bins[c]);
}

// ---------- launch ----------
extern "C" void kernel_launch(void* const* d_in, const int* in_sizes, int n_in,
                              void* d_out, int out_size, void* d_ws, size_t ws_size,
                              hipStream_t stream) {
    const float* image_features = (const float*)d_in[0];   // [N, D]
    const float* text_embeds    = (const float*)d_in[1];   // [C, D]
    const float* support_feats  = (const float*)d_in[2];   // [D, M]
    const int*   support_labels = (const int*)d_in[3];     // [M]
    float* out = (float*)d_out;

    char* base = (char*)d_ws;
    size_t off = 0;
    auto alloc = [&](size_t bytes) {
        void* p = base + off;
        off = (off + bytes + 255) & ~(size_t)255;
        return p;
    };
    short* Tnb  = (short*)alloc(sizeof(short) * C_CLS * D_DIM);   // normalized text bf16 [C, D]
    short* TnT  = (short*)alloc(sizeof(short) * D_DIM * C_PAD);   // transposed text bf16 [D, 1024]
    short* imgb = (short*)alloc(sizeof(short) * N_IMG * D_DIM);   // normalized image bf16 [N, D]
    short* Sb   = (short*)alloc(sizeof(short) * M_SUP * D_DIM);   // support^T bf16 [M, D]
    short* pb   = (short*)alloc(sizeof(short) * N_IMG * C_PAD);   // test probs bf16 [N, 1024]
    short* Wb   = (short*)alloc(sizeof(short) * N_IMG * D_DIM);   // 2*pb.Tnb bf16 [N, D]
    float* dot  = (float*)alloc(sizeof(float) * N_IMG * C_PAD);   // img @ Tn^T fp32 [N, 1024]
    float* se   = (float*)alloc(sizeof(float) * M_SUP);           // sum_c exp(train logits)
    float* ent  = (float*)alloc(sizeof(float) * N_IMG);
    float* kl   = (float*)alloc(sizeof(float) * N_IMG * M_SUP);   // KL divergences
    float* nk   = (float*)alloc(sizeof(float) * N_IMG * M_SUP);   // img @ S
    unsigned* mm = (unsigned*)alloc(256);

    // 1. prep: init + normalize x2 + S transpose + se zero (all coalesced)
    prep_k<<<3416, 256, 0, stream>>>(
        text_embeds, image_features, support_feats, Tnb, imgb, Sb, se, mm);

    // 2. mega GEMM: GEMM1-fused-LSE + GEMM3 + GEMM0 (mutually independent)
    mega_gemm_k<<<1544, 256, 0, stream>>>(Sb, Tnb, imgb, se, nk, dot, mm, out);

    // 3. softmax (needs dot) + TnT tile-transpose (needs Tnb) - co-dispatched
    sm_tr_k<<<228, 256, 0, stream>>>(dot, pb, ent, Tnb, TnT);

    // 4. W GEMM (needs pb, TnT)
    wgemm_k<<<16, 256, 0, stream>>>(pb, TnT, Wb);

    // 5. qGEMM: kl + minmax (needs Wb, Sb, ent, se)
    qgemm_k<<<512, 256, 0, stream>>>(Wb, Sb, kl, ent, se, mm);

    // 6. final
    final_partial_k<<<dim3(N_IMG, 4), 256, 0, stream>>>(kl, nk, support_labels, mm, out);
}

// Round 13
// 210.087 us; speedup vs baseline: 1.0713x; 1.0472x over previous
//
#include <hip/hip_runtime.h>
#include <math.h>

#define TEMP_F   0.5f
#define ALPHA_F  1.0f
#define BETA_F   5.5f
#define GAMMA_F  5.0f
#define N_IMG    400
#define D_DIM    512
#define C_CLS    1000
#define C_PAD    1024
#define M_SUP    16000

typedef __attribute__((ext_vector_type(8))) short short8;
typedef __attribute__((ext_vector_type(4))) short short4v;
typedef __attribute__((ext_vector_type(4))) float f32x4;

// ---------- helpers ----------
__device__ __forceinline__ short f2bf(float f) {
    unsigned u = __float_as_uint(f);
    unsigned r = (u + 0x7fffu + ((u >> 16) & 1u)) >> 16;
    return (short)r;
}
__device__ __forceinline__ float bf2f(short s) {
    return __uint_as_float(((unsigned)(unsigned short)s) << 16);
}
__device__ __forceinline__ unsigned encf(float f) {
    unsigned u = __float_as_uint(f);
    return (u & 0x80000000u) ? ~u : (u | 0x80000000u);
}
__device__ __forceinline__ float decf(unsigned u) {
    return (u & 0x80000000u) ? __uint_as_float(u & 0x7FFFFFFFu) : __uint_as_float(~u);
}

__device__ __forceinline__ float block_reduce_sum(float v) {
    __shared__ float red[4];
    #pragma unroll
    for (int o = 32; o > 0; o >>= 1) v += __shfl_down(v, o, 64);
    int w = threadIdx.x >> 6, l = threadIdx.x & 63;
    __syncthreads();
    if (l == 0) red[w] = v;
    __syncthreads();
    float r = red[0];
    int nw = blockDim.x >> 6;
    for (int i = 1; i < nw; ++i) r += red[i];
    return r;
}

__device__ __forceinline__ void gload_lds16(const void* g, void* l) {
    __builtin_amdgcn_global_load_lds(
        (const __attribute__((address_space(1))) unsigned int*)g,
        (__attribute__((address_space(3))) unsigned int*)l, 16, 0, 0);
}

// ---------- shared GEMM body ----------
// bf16 MFMA GEMM tile: C[i,j] = alpha * sum_k A[i,k]*B[j,k]
// 128x128 tile, BK=32, 4 waves, counted-vmcnt 3-buffer pipeline (T3+T4+T5).
// BEST-MEASURED CONFIGURATION (round 7, 212.8 us) - restored verbatim after
// rounds 8-12 proved every variant family null or negative at this size:
//   r8  one-barrier 4-buf + lane-swizzle: null (conflicts = address-set
//       property, bit-identical count; barrier not dominant)
//   r9  128x256 wide tile: null (MfmaUtil 17.7 vs 17.4)
//   r10 unfenced-MFMA read order: -4.3 us
//   r11/r12 W-factorization (less FLOPs, more dispatches): +7-12 us
// MfmaUtil ~17% is on the guide's measured shape-curve for K=512 tiles;
// the structure is latency/serialization-limited at problem scale, not
// fixable by K-loop scheduling.
// No vmem stores outstanding during the K-loop (round-3 lesson).
// EPILOGUE ATOMIC RULE (round-5/6, confirmed): minmax funnels through an
// LDS reduce to ONE atomicMin + ONE atomicMax per block; per-wave
// same-address atomics serialize chip-wide (~50 us kernel-exit tail).
// EPI: 1 = bf16 store
//      2 = kl transform (v = ent[i] - v + lse[j]) fp32 store + minmax mm[0..1]
//      3 = fp32 store + minmax mm[2..3]
//      4 = fp32 store + 100*v pre-fill into out2 [I x C_CLS]
template<int EPI>
__device__ __forceinline__ void gemm_body(
    const short* __restrict__ A, const short* __restrict__ B, void* __restrict__ Cm,
    int I, int Jclamp, int Jout, int K, long lda, long ldb, long ldc, float alpha,
    const float* __restrict__ ent, const float* __restrict__ lse,
    unsigned* __restrict__ mm, float* __restrict__ out2,
    int i0, int j0, short (*As)[4096], short (*Bs)[4096])
{
    const int tid = threadIdx.x;
    const int wave = tid >> 6;
    const int lane = tid & 63;

    const int srow = wave * 16 + (lane >> 2);  // staging row within 64-row group
    const int skk  = (lane & 3) * 8;           // staging k offset (bf16 elems)

    const int wm = (wave & 1) * 64;
    const int wn = (wave >> 1) * 64;
    const int fr = lane & 15;   // fragment row/col
    const int fq = lane >> 4;   // quad

    f32x4 acc[4][4] = {};

    auto stage = [&](int buf, int k0) {
        #pragma unroll
        for (int q = 0; q < 2; ++q) {
            int gi = i0 + q * 64 + srow; if (gi > I - 1) gi = I - 1;
            gload_lds16(A + (long)gi * lda + k0 + skk, As[buf] + q * 2048 + wave * 512);
        }
        #pragma unroll
        for (int q = 0; q < 2; ++q) {
            int gj = j0 + q * 64 + srow; if (gj > Jclamp - 1) gj = Jclamp - 1;
            gload_lds16(B + (long)gj * ldb + k0 + skk, Bs[buf] + q * 2048 + wave * 512);
        }
    };

    const int nt = K >> 5;                 // 16 or 32
    stage(0, 0);
    if (nt > 1) stage(1, 32);
    if (nt > 2) stage(2, 64);              // 12 loads/wave outstanding

    for (int t = 0; t < nt; ++t) {
        const int b = t % 3;

        // wait for tile t's 4 loads (this wave); keep t+1,t+2 in flight
        if (t + 2 < nt)      asm volatile("s_waitcnt vmcnt(8)" ::: "memory");
        else if (t + 1 < nt) asm volatile("s_waitcnt vmcnt(4)" ::: "memory");
        else                 asm volatile("s_waitcnt vmcnt(0)" ::: "memory");
        __builtin_amdgcn_s_barrier();      // all waves' tile-t staging visible
        __builtin_amdgcn_sched_barrier(0);

        short8 af[4], bfr[4];
        #pragma unroll
        for (int mi = 0; mi < 4; ++mi)
            af[mi] = *(const short8*)(As[b] + (wm + mi * 16 + fr) * 32 + fq * 8);
        #pragma unroll
        for (int ni = 0; ni < 4; ++ni)
            bfr[ni] = *(const short8*)(Bs[b] + (wn + ni * 16 + fr) * 32 + fq * 8);

        asm volatile("s_waitcnt lgkmcnt(0)" ::: "memory");   // frags in regs
        __builtin_amdgcn_sched_barrier(0);
        __builtin_amdgcn_s_barrier();      // all waves done READING buf b

        if (t + 3 < nt) stage(b, (t + 3) << 5);   // restage freed buffer

        __builtin_amdgcn_s_setprio(1);
        #pragma unroll
        for (int mi = 0; mi < 4; ++mi)
            #pragma unroll
            for (int ni = 0; ni < 4; ++ni)
                acc[mi][ni] = __builtin_amdgcn_mfma_f32_16x16x32_bf16(
                    af[mi], bfr[ni], acc[mi][ni], 0, 0, 0);
        __builtin_amdgcn_s_setprio(0);
    }

    float lmin = INFINITY, lmax = -INFINITY;

    #pragma unroll
    for (int mi = 0; mi < 4; ++mi) {
        #pragma unroll
        for (int ni = 0; ni < 4; ++ni) {
            int gj = j0 + wn + ni * 16 + fr;
            float lsev = 0.f;
            if (EPI == 2) lsev = lse[gj < Jout ? gj : (Jout - 1)];
            #pragma unroll
            for (int t = 0; t < 4; ++t) {
                int gi = i0 + wm + mi * 16 + fq * 4 + t;
                float v = alpha * acc[mi][ni][t];
                if (EPI == 2) {
                    int gic = gi < I ? gi : (I - 1);
                    v = ent[gic] - v + lsev;
                }
                if (EPI == 2 || EPI == 3) { lmin = fminf(lmin, v); lmax = fmaxf(lmax, v); }
                if (gi < I && gj < Jout) {
                    if (EPI == 1) ((short*)Cm)[(long)gi * ldc + gj] = f2bf(v);
                    else          ((float*)Cm)[(long)gi * ldc + gj] = v;
                }
                if (EPI == 4 && gi < I && gj < C_CLS)
                    out2[(long)gi * C_CLS + gj] = 100.f * v;
            }
        }
    }

    if (EPI == 2 || EPI == 3) {
        // per-wave shuffle reduce -> LDS -> ONE atomicMin/Max per block.
        #pragma unroll
        for (int o = 32; o > 0; o >>= 1) {
            lmin = fminf(lmin, __shfl_down(lmin, o, 64));
            lmax = fmaxf(lmax, __shfl_down(lmax, o, 64));
        }
        __shared__ float rmin[4], rmax[4];
        if (lane == 0) { rmin[wave] = lmin; rmax[wave] = lmax; }
        __syncthreads();
        if (tid == 0) {
            float bmin = fminf(fminf(rmin[0], rmin[1]), fminf(rmin[2], rmin[3]));
            float bmax = fmaxf(fmaxf(rmax[0], rmax[1]), fmaxf(rmax[2], rmax[3]));
            const int base = (EPI == 2) ? 0 : 2;
            atomicMin(&mm[base + 0], encf(bmin));
            atomicMax(&mm[base + 1], encf(bmax));
        }
    }
}

// ---------- kernels ----------

// prep: init mm + normalize text rows (blocks 0..999) + normalize image rows
// (1000..1399) + transpose S into Sb (1400..3399, 250x8 64x64 tiles).
__global__ __launch_bounds__(256) void prep_k(
    const float* __restrict__ text_embeds, const float* __restrict__ image_features,
    const float* __restrict__ S,
    short* __restrict__ Tnb, short* __restrict__ imgb, short* __restrict__ Sb,
    unsigned* __restrict__ mm)
{
    const int b = blockIdx.x;
    if (b == 0 && threadIdx.x < 4)
        mm[threadIdx.x] = (threadIdx.x & 1) ? encf(-INFINITY) : encf(INFINITY);

    if (b < 1400) {
        const float* s;
        short* d;
        if (b < 1000) { s = text_embeds + (long)b * D_DIM;            d = Tnb  + (long)b * D_DIM; }
        else          { s = image_features + (long)(b - 1000) * D_DIM; d = imgb + (long)(b - 1000) * D_DIM; }
        float ss = 0.f;
        for (int c = threadIdx.x; c < D_DIM; c += 256) { float v = s[c]; ss += v * v; }
        float tot = block_reduce_sum(ss);
        float inv = 1.0f / fmaxf(sqrtf(tot), 1e-12f);
        for (int c = threadIdx.x; c < D_DIM; c += 256) d[c] = f2bf(s[c] * inv);
    } else {
        __shared__ float tile[64][65];
        int l = b - 1400;
        int m0 = (l % 250) * 64, d0 = (l / 250) * 64;
        int ml = (threadIdx.x & 15) * 4;
        int dl = threadIdx.x >> 4;
        #pragma unroll
        for (int r = 0; r < 64; r += 16) {
            f32x4 v = *(const f32x4*)(S + (long)(d0 + dl + r) * M_SUP + m0 + ml);
            tile[dl + r][ml + 0] = v[0];
            tile[dl + r][ml + 1] = v[1];
            tile[dl + r][ml + 2] = v[2];
            tile[dl + r][ml + 3] = v[3];
        }
        __syncthreads();
        int mw = threadIdx.x >> 4;
        int dc = (threadIdx.x & 15) * 4;
        #pragma unroll
        for (int r = 0; r < 64; r += 16) {
            short4v o;
            #pragma unroll
            for (int k = 0; k < 4; ++k) o[k] = f2bf(tile[dc + k][mw + r]);
            *(short4v*)(Sb + (long)(m0 + mw + r) * D_DIM + d0 + dc) = o;
        }
    }
}

// mega GEMM: three independent GEMMs in one dispatch (grid-partition fusion).
// blocks [0,1000):    GEMM1 tb = 2*Sb.Tnb^T  (125 i x 8 j, bijective XCD
//   swizzle: each XCD owns a contiguous i-band iterating all 8 j -> Sb
//   stripe fetched by ONE XCD, Tnb L2-resident)
// blocks [1000,1512): GEMM3 nk = imgb.Sb^T   (4 i x 128 j, XCD-grouped)
//                     + minmax mm[2..3]
// blocks [1512,1544): GEMM0 dot = imgb.Tnb^T (4 i x 8 j) + out prefill
__global__ __launch_bounds__(256) void mega_gemm_k(
    const short* __restrict__ Sb, const short* __restrict__ Tnb,
    const short* __restrict__ imgb,
    short* __restrict__ tb, float* __restrict__ nk, float* __restrict__ dot,
    unsigned* __restrict__ mm, float* __restrict__ out)
{
    __shared__ short As[3][4096];
    __shared__ short Bs[3][4096];
    const int lin = blockIdx.x;

    if (lin < 1000) {
        int gt = (lin & 7) * 125 + (lin >> 3);   // bijective [0,1000)
        int i0 = (gt >> 3) * 128;                // 125 i-tiles
        int j0 = (gt & 7) * 128;                 // 8 j-tiles
        gemm_body<1>(Sb, Tnb, tb, M_SUP, C_CLS, C_PAD, D_DIM, D_DIM, D_DIM, C_PAD,
                     2.0f, nullptr, nullptr, nullptr, nullptr, i0, j0, As, Bs);
    } else if (lin < 1512) {
        int l = lin - 1000;
        int xcd = l & 7;
        int idx = l >> 3;
        int i0 = (idx & 3) * 128;
        int j0 = (xcd * 16 + (idx >> 2)) * 128;
        gemm_body<3>(imgb, Sb, nk, N_IMG, M_SUP, M_SUP, D_DIM, D_DIM, D_DIM, M_SUP,
                     1.0f, nullptr, nullptr, mm, nullptr, i0, j0, As, Bs);
    } else {
        int l = lin - 1512;                      // 32 blocks: 4 i x 8 j
        int i0 = (l >> 3) * 128;
        int j0 = (l & 7) * 128;
        gemm_body<4>(imgb, Tnb, dot, N_IMG, C_CLS, C_PAD, D_DIM, D_DIM, D_DIM, C_PAD,
                     1.0f, nullptr, nullptr, nullptr, out, i0, j0, As, Bs);
    }
}

// merged row_lse (blocks 0..3999) + test softmax (4000..4099).
// One wave per row, data in registers, butterfly reduces, zero barriers.
__global__ void lse_softmax_k(
    const short* __restrict__ tb, float* __restrict__ lse,
    const float* __restrict__ dot, short* __restrict__ pb, float* __restrict__ ent)
{
    const int b = blockIdx.x;
    const int lane = threadIdx.x & 63;
    if (b < 4000) {
        int row = b * 4 + (threadIdx.x >> 6);
        const short* r = tb + (long)row * C_PAD;
        short8 v0 = *(const short8*)(r + lane * 8);
        short8 v1 = *(const short8*)(r + 512 + lane * 8);
        bool act1 = lane < 61;                 // cols 512+lane*8 < 1000
        float f0[8], f1[8];
        float mx = -INFINITY;
        #pragma unroll
        for (int j = 0; j < 8; ++j) { f0[j] = bf2f(v0[j]); mx = fmaxf(mx, f0[j]); }
        if (act1) {
            #pragma unroll
            for (int j = 0; j < 8; ++j) { f1[j] = bf2f(v1[j]); mx = fmaxf(mx, f1[j]); }
        }
        #pragma unroll
        for (int o = 32; o > 0; o >>= 1) mx = fmaxf(mx, __shfl_xor(mx, o, 64));
        float se = 0.f;
        #pragma unroll
        for (int j = 0; j < 8; ++j) se += __expf(f0[j] - mx);
        if (act1) {
            #pragma unroll
            for (int j = 0; j < 8; ++j) se += __expf(f1[j] - mx);
        }
        #pragma unroll
        for (int o = 32; o > 0; o >>= 1) se += __shfl_xor(se, o, 64);
        if (lane == 0) lse[row] = mx + __logf(se);
    } else {
        int n = (b - 4000) * 4 + (threadIdx.x >> 6);
        const float* dr = dot + (long)n * C_PAD;
        short* pr = pb + (long)n * C_PAD;
        f32x4 v[4];
        #pragma unroll
        for (int pp = 0; pp < 4; ++pp)
            v[pp] = *(const f32x4*)(dr + pp * 256 + lane * 4);
        float mx = -INFINITY;
        #pragma unroll
        for (int pp = 0; pp < 4; ++pp) {
            bool valid = (pp < 3) || (lane < 58);   // col 768+lane*4 < 1000
            if (valid)
                #pragma unroll
                for (int j = 0; j < 4; ++j) mx = fmaxf(mx, 2.f * v[pp][j]);
        }
        #pragma unroll
        for (int o = 32; o > 0; o >>= 1) mx = fmaxf(mx, __shfl_xor(mx, o, 64));
        float se = 0.f;
        #pragma unroll
        for (int pp = 0; pp < 4; ++pp) {
            bool valid = (pp < 3) || (lane < 58);
            if (valid)
                #pragma unroll
                for (int j = 0; j < 4; ++j) se += __expf(2.f * v[pp][j] - mx);
        }
        #pragma unroll
        for (int o = 32; o > 0; o >>= 1) se += __shfl_xor(se, o, 64);
        float logsum = mx + __logf(se);
        float e = 0.f;
        #pragma unroll
        for (int pp = 0; pp < 4; ++pp) {
            bool valid = (pp < 3) || (lane < 58);
            short4v o4;
            #pragma unroll
            for (int j = 0; j < 4; ++j) {
                if (valid) {
                    float lp = 2.f * v[pp][j] - logsum;
                    float pv = __expf(lp);
                    o4[j] = f2bf(pv);
                    e += pv * lp;
                } else {
                    o4[j] = 0;
                }
            }
            *(short4v*)(pr + pp * 256 + lane * 4) = o4;
        }
        #pragma unroll
        for (int o = 32; o > 0; o >>= 1) e += __shfl_xor(e, o, 64);
        if (lane == 0) ent[n] = e;
    }
}

// GEMM2: kl = ent[i] - pb.tb^T + lse[j]  (K=1024) + minmax mm[0..1].
// Depends on lse_softmax output -> cannot merge into mega.
__global__ __launch_bounds__(256) void gemm2_k(
    const short* __restrict__ pb, const short* __restrict__ tb, float* __restrict__ kl,
    const float* __restrict__ ent, const float* __restrict__ lse,
    unsigned* __restrict__ mm)
{
    __shared__ short As[3][4096];
    __shared__ short Bs[3][4096];
    int lin = blockIdx.x;                  // 512 blocks: 4 i x 128 j, XCD-grouped
    int xcd = lin & 7;
    int idx = lin >> 3;
    int i0 = (idx & 3) * 128;
    int j0 = (xcd * 16 + (idx >> 2)) * 128;
    gemm_body<2>(pb, tb, kl, N_IMG, M_SUP, M_SUP, C_PAD, C_PAD, C_PAD, M_SUP,
                 1.0f, ent, lse, mm, nullptr, i0, j0, As, Bs);
}

// M split 4 ways (1600 blocks). float4/int4 loads. out was pre-filled with
// 100*dot by mega's GEMM0 branch; partial class bins merged with one
// coalesced global atomicAdd per class (distinct addresses, contention 4).
__global__ __launch_bounds__(256) void final_partial_k(
    const float* __restrict__ kl, const float* __restrict__ nk,
    const int* __restrict__ labels, const unsigned* __restrict__ mm,
    float* __restrict__ out)
{
    int n = blockIdx.x;
    int q = blockIdx.y;                       // 0..3, quarter of M
    __shared__ float bins[C_CLS];
    for (int c = threadIdx.x; c < C_CLS; c += 256) bins[c] = 0.f;
    __syncthreads();
    float klmin = decf(mm[0]), klmax = decf(mm[1]);
    float nkmin = decf(mm[2]), nkmax = decf(mm[3]);
    float ratio = (nkmax - nkmin) / (klmax - klmin);
    const int m0 = q * (M_SUP / 4);
    const float4* kl4 = (const float4*)(kl + (long)n * M_SUP + m0);
    const float4* nk4 = (const float4*)(nk + (long)n * M_SUP + m0);
    const int4*  lb4 = (const int4*)(labels + m0);
    const int nv = M_SUP / 4 / 4;             // 1000 float4s per quarter
    for (int v = threadIdx.x; v < nv; v += 256) {
        float4 kv = kl4[v];
        float4 vv = nk4[v];
        int4   lv = lb4[v];
        float y, contrib;
        y = (kv.x - klmin) * ratio + nkmin;
        contrib = -GAMMA_F * y + ALPHA_F * __expf(BETA_F * (vv.x - 1.0f));
        atomicAdd(&bins[lv.x], contrib);
        y = (kv.y - klmin) * ratio + nkmin;
        contrib = -GAMMA_F * y + ALPHA_F * __expf(BETA_F * (vv.y - 1.0f));
        atomicAdd(&bins[lv.y], contrib);
        y = (kv.z - klmin) * ratio + nkmin;
        contrib = -GAMMA_F * y + ALPHA_F * __expf(BETA_F * (vv.z - 1.0f));
        atomicAdd(&bins[lv.z], contrib);
        y = (kv.w - klmin) * ratio + nkmin;
        contrib = -GAMMA_F * y + ALPHA_F * __expf(BETA_F * (vv.w - 1.0f));
        atomicAdd(&bins[lv.w], contrib);
    }
    __syncthreads();
    for (int c = threadIdx.x; c < C_CLS; c += 256)
        atomicAdd(&out[(long)n * C_CLS + c], bins[c]);
}

// ---------- launch ----------
extern "C" void kernel_launch(void* const* d_in, const int* in_sizes, int n_in,
                              void* d_out, int out_size, void* d_ws, size_t ws_size,
                              hipStream_t stream) {
    const float* image_features = (const float*)d_in[0];   // [N, D]
    const float* text_embeds    = (const float*)d_in[1];   // [C, D]
    const float* support_feats  = (const float*)d_in[2];   // [D, M]
    const int*   support_labels = (const int*)d_in[3];     // [M]
    float* out = (float*)d_out;

    char* base = (char*)d_ws;
    size_t off = 0;
    auto alloc = [&](size_t bytes) {
        void* p = base + off;
        off = (off + bytes + 255) & ~(size_t)255;
        return p;
    };
    short* Tnb  = (short*)alloc(sizeof(short) * C_CLS * D_DIM);   // normalized text bf16 [C, D]
    short* imgb = (short*)alloc(sizeof(short) * N_IMG * D_DIM);   // normalized image bf16 [N, D]
    short* Sb   = (short*)alloc(sizeof(short) * M_SUP * D_DIM);   // support^T bf16 [M, D]
    short* tb   = (short*)alloc(sizeof(short) * M_SUP * C_PAD);   // train logits bf16 [M, 1024]
    short* pb   = (short*)alloc(sizeof(short) * N_IMG * C_PAD);   // test probs bf16 [N, 1024]
    float* dot  = (float*)alloc(sizeof(float) * N_IMG * C_PAD);   // img @ Tn^T fp32 [N, 1024]
    float* lse  = (float*)alloc(sizeof(float) * M_SUP);
    float* ent  = (float*)alloc(sizeof(float) * N_IMG);
    float* kl   = (float*)alloc(sizeof(float) * N_IMG * M_SUP);   // KL divergences
    float* nk   = (float*)alloc(sizeof(float) * N_IMG * M_SUP);   // img @ S
    unsigned* mm = (unsigned*)alloc(256);

    // 1. prep: init + normalize x2 + transpose (all independent)
    prep_k<<<3400, 256, 0, stream>>>(
        text_embeds, image_features, support_feats, Tnb, imgb, Sb, mm);

    // 2. mega GEMM: GEMM1 + GEMM3 + GEMM0 (mutually independent)
    mega_gemm_k<<<1544, 256, 0, stream>>>(Sb, Tnb, imgb, tb, nk, dot, mm, out);

    // 3. row_lse + test_softmax (independent of each other)
    lse_softmax_k<<<4100, 256, 0, stream>>>(tb, lse, dot, pb, ent);

    // 4. GEMM2 (needs pb, ent, lse)
    gemm2_k<<<512, 256, 0, stream>>>(pb, tb, kl, ent, lse, mm);

    // 5. final
    final_partial_k<<<dim3(N_IMG, 4), 256, 0, stream>>>(kl, nk, support_labels, mm, out);
}